// Round 3
// baseline (506.805 us; speedup 1.0000x reference)
//
#include <hip/hip_runtime.h>

// Problem constants
#define NN    65536       // H*W (H=W=256)
#define NSUB  256         // n per block
#define NBLK  (NN/NSUB)   // 256 blocks per batch
#define CPAD  65          // xs[n][c] stride: b32 access banks (n+c)%32 -> 2-way (free)

// workspace layout (float offsets)
#define OFF_W   0
#define SZ_W    (8*64*24)          // Weff[b][c][h*3+j]
#define OFF_CJ  (OFF_W + SZ_W)
#define SZ_CJ   (8*24)
#define OFF_PM  (OFF_CJ + SZ_CJ)
#define SZ_P    (8*NBLK*8)         // per (b,blk,h)
#define OFF_PL  (OFF_PM + SZ_P)
#define OFF_PSP (OFF_PL + SZ_P)    // [..][2]
#define OFF_PSX (OFF_PSP + 2*SZ_P) // [..][64]
#define SZ_PSX  (8*NBLK*8*64)
#define OFF_Q   (OFF_PSX + SZ_PSX) // per (b,h,g): m,l,spx,spy,sx[64] stride 68
#define QSTR    68

// LDS: xs[256][65] + red[128] = 16768 floats = 67072 B -> 2 blocks/CU
#define SMEM1_FLOATS (NSUB*CPAD + 128)
#define SMEM1_BYTES  (SMEM1_FLOATS*4)

// ---------------- K0: per-(b,h) effective weights ----------------
__global__ __launch_bounds__(64) void prep_kernel(
    const float* __restrict__ z,  const float* __restrict__ Wq, const float* __restrict__ bq,
    const float* __restrict__ Wk, const float* __restrict__ bk,
    const float* __restrict__ Wp, const float* __restrict__ bp,
    float* __restrict__ Weff, float* __restrict__ Cj)
{
  const int h = blockIdx.x, b = blockIdx.y, t = threadIdx.x;
  __shared__ float q[32];
  if (t < 32) {
    const int e = h*32 + t;
    float a = bq[e];
    const float* zr = z + b*64;
    const float* wr = Wq + e*64;
    #pragma unroll 8
    for (int c = 0; c < 64; ++c) a += zr[c]*wr[c];
    q[t] = a;
  }
  __syncthreads();
  {
    const int c = t;
    float w0 = 0.f, w1 = 0.f, w2 = 0.f;
    #pragma unroll 4
    for (int hd = 0; hd < 32; ++hd) {
      const float qk = q[hd] * Wk[(h*32+hd)*64 + c];
      w0 += qk * bp[hd];
      w1 += qk * Wp[hd*2+0];
      w2 += qk * Wp[hd*2+1];
    }
    float* o = Weff + (b*64 + c)*24 + h*3;
    o[0] = w0; o[1] = w1; o[2] = w2;
  }
  if (t < 3) {
    float s = 0.f;
    for (int hd = 0; hd < 32; ++hd) {
      const float m = (t == 0) ? bp[hd] : Wp[hd*2 + (t-1)];
      s += q[hd] * m * bk[h*32+hd];
    }
    Cj[b*24 + h*3 + t] = s;
  }
}

// ---------------- K1: fused logits + block-softmax partials + weighted-x ----------------
// x column in VGPRs (phase A: pure v_fmac with s_load'ed w). LDS holds x^T for phase B only.
// Phase B p-operand comes from v_readlane of this wave's own registers (VALU, not DS).
__global__ __launch_bounds__(256, 2) void main_kernel(
    const float* __restrict__ x, const float* __restrict__ pos,
    const float* __restrict__ Weff, const float* __restrict__ Cj,
    float* __restrict__ Pm, float* __restrict__ Pl,
    float* __restrict__ Psp, float* __restrict__ Psx)
{
  extern __shared__ float sm[];
  float* xs  = sm;                 // [256][CPAD] x^T
  float* red = sm + NSUB*CPAD;     // [128]: [0..31] max, [32..63] sum p, [64..95] sum p*j
  const int t   = threadIdx.x;
  const int blk = blockIdx.x;
  const int b   = blockIdx.y;
  const int n0  = blk * NSUB;
  const int wid = t >> 6, lid = t & 63;

  // ---- load x[b, :, n0+t] into 64 VGPRs (coalesced b32 per c) + transpose into LDS ----
  float vx[64];
  {
    const float* xg = x + (size_t)b*64*NN + n0 + t;
    #pragma unroll
    for (int c = 0; c < 64; ++c) vx[c] = xg[(size_t)c*NN];
    #pragma unroll
    for (int c = 0; c < 64; ++c) xs[t*CPAD + c] = vx[c];   // banks (t+c)%32: 2-way, free
  }

  // ---- phase A: logits, zero LDS. w via wave-uniform pointer -> s_load. ----
  float acc[24];
  {
    const float* cjp = Cj + b*24;
    #pragma unroll
    for (int k = 0; k < 24; ++k) acc[k] = cjp[k];
  }
  {
    const float* wb = Weff + b*1536;
    #pragma unroll
    for (int c = 0; c < 64; ++c) {
      const float xv = vx[c];
      const float* wr = wb + c*24;       // block-uniform -> SGPRs
      #pragma unroll
      for (int k = 0; k < 24; ++k) acc[k] += wr[k]*xv;
    }
  }
  float lg[8];
  {
    const float gx = (float)blk;          // n>>8 == blk, block-uniform
    const float ty = (float)t;            // n&255 == t
    #pragma unroll
    for (int h = 0; h < 8; ++h) {
      const float rx = gx - pos[(b*8+h)*2 + 0];
      const float ry = ty - pos[(b*8+h)*2 + 1];
      lg[h] = (acc[h*3+0] + rx*acc[h*3+1] + ry*acc[h*3+2]) * 0.17677669529663687f;
    }
  }

  // ---- block max per head ----
  #pragma unroll
  for (int h = 0; h < 8; ++h) {
    float m = lg[h];
    #pragma unroll
    for (int off = 32; off >= 1; off >>= 1) m = fmaxf(m, __shfl_xor(m, off, 64));
    if (lid == 0) red[h*4 + wid] = m;
  }
  __syncthreads();   // also publishes xs for phase B

  // ---- exp + per-wave quarter sums (p, p*j) ----
  float p[8];
  #pragma unroll
  for (int h = 0; h < 8; ++h) {
    const float M = fmaxf(fmaxf(red[h*4+0], red[h*4+1]), fmaxf(red[h*4+2], red[h*4+3]));
    p[h] = __expf(lg[h] - M);
  }
  {
    const float lf = (float)lid;
    #pragma unroll
    for (int h = 0; h < 8; ++h) {
      float sp  = p[h];
      float spj = p[h]*lf;
      #pragma unroll
      for (int off = 32; off >= 1; off >>= 1) {
        sp  += __shfl_xor(sp,  off, 64);
        spj += __shfl_xor(spj, off, 64);
      }
      if (lid == 0) { red[32 + h*4 + wid] = sp; red[64 + h*4 + wid] = spj; }
    }
  }
  __syncthreads();

  if (t < 8) {   // head t: combine 4 quarter-sums, write partials
    const int base = (b*NBLK + blk)*8 + t;
    const float M = fmaxf(fmaxf(red[t*4+0], red[t*4+1]), fmaxf(red[t*4+2], red[t*4+3]));
    float L = 0.f, SJ = 0.f;
    #pragma unroll
    for (int w = 0; w < 4; ++w) {
      const float sp = red[32 + t*4 + w];
      L  += sp;
      SJ += 64.0f*(float)w*sp + red[64 + t*4 + w];   // global n = 64w + j
    }
    Pm[base] = M;
    Pl[base] = L;
    Psp[base*2+0] = (float)blk * L;   // sum p*gx, gx uniform
    Psp[base*2+1] = SJ;               // sum p*gy
  }

  // ---- phase B: aB[h][c=lid] = sum_{n in quarter} p[h][n] * x[n][c] ----
  // p via v_readlane from own wave (VALU); x via b32 column reads (2-way, free).
  float aB[8];
  #pragma unroll
  for (int h = 0; h < 8; ++h) aB[h] = 0.f;
  {
    const float* xcol = xs + wid*64*CPAD + lid;
    #pragma unroll 8
    for (int j = 0; j < 64; ++j) {
      const float xv = xcol[j*CPAD];
      #pragma unroll
      for (int h = 0; h < 8; ++h) {
        const float pj = __int_as_float(__builtin_amdgcn_readlane(__float_as_int(p[h]), j));
        aB[h] = fmaf(pj, xv, aB[h]);
      }
    }
  }
  __syncthreads();                     // all xs reads done; reuse region for partials
  #pragma unroll
  for (int h = 0; h < 8; ++h) sm[(wid*8 + h)*64 + lid] = aB[h];
  __syncthreads();
  {
    const int pb = (b*NBLK + blk)*8;
    #pragma unroll
    for (int r = 0; r < 2; ++r) {
      const int idx = t + 256*r;        // (h,c) flat
      const float s = sm[idx] + sm[512+idx] + sm[1024+idx] + sm[1536+idx];
      Psx[(size_t)pb*64 + idx] = s;
    }
  }
}

// ---------------- K2a: combine 32 blocks per (b,h,g) with local max ----------------
__global__ __launch_bounds__(256) void reduce1_kernel(
    const float* __restrict__ Pm, const float* __restrict__ Pl,
    const float* __restrict__ Psp, const float* __restrict__ Psx,
    float* __restrict__ Q)
{
  const int g = blockIdx.x, h = blockIdx.y, b = blockIdx.z, t = threadIdx.x;
  __shared__ float al[32];
  __shared__ float mgs;
  __shared__ float sums[3];
  __shared__ float sxl[256];
  const int base = (b*NBLK + g*32)*8 + h;   // + k*8 for block g*32+k

  float m_t = -1e30f;
  if (t < 32) m_t = Pm[base + t*8];
  if (t < 64) {
    float mm = m_t;
    #pragma unroll
    for (int off = 16; off >= 1; off >>= 1) mm = fmaxf(mm, __shfl_xor(mm, off, 64));
    if (t == 0) mgs = mm;
  }
  __syncthreads();
  const float Mg = mgs;
  if (t < 32) {
    const float a = __expf(m_t - Mg);
    al[t] = a;
    float lt  = Pl[base + t*8] * a;
    float sx  = Psp[(base + t*8)*2 + 0] * a;
    float sy  = Psp[(base + t*8)*2 + 1] * a;
    #pragma unroll
    for (int off = 16; off >= 1; off >>= 1) {
      lt += __shfl_xor(lt, off, 64);
      sx += __shfl_xor(sx, off, 64);
      sy += __shfl_xor(sy, off, 64);
    }
    if (t == 0) { sums[0] = lt; sums[1] = sx; sums[2] = sy; }
  }
  __syncthreads();
  {
    const int c = t & 63, g2 = t >> 6;
    float acc = 0.f;
    #pragma unroll
    for (int i = 0; i < 8; ++i) {
      const int k = g2*8 + i;
      acc += al[k] * Psx[(size_t)(base + k*8)*64 + c];
    }
    sxl[g2*64 + c] = acc;
  }
  __syncthreads();
  float* q = Q + ((b*8 + h)*8 + g)*QSTR;
  if (t < 64) q[4+t] = sxl[t] + sxl[64+t] + sxl[128+t] + sxl[192+t];
  if (t == 0) { q[0] = Mg; q[1] = sums[0]; q[2] = sums[1]; q[3] = sums[2]; }
}

// ---------------- K2b: final combine + value projection ----------------
__global__ __launch_bounds__(64) void reduce2_kernel(
    const float* __restrict__ Q, const float* __restrict__ Wv, const float* __restrict__ bv,
    float* __restrict__ out)
{
  const int h = blockIdx.x, b = blockIdx.y, t = threadIdx.x;
  __shared__ float qm[8], bl[8], l8[8], sx8[8], sy8[8];
  __shared__ float SXs[64];
  const float* qb = Q + ((b*8 + h)*8)*QSTR;

  if (t < 8) qm[t] = qb[t*QSTR + 0];
  __syncthreads();
  float M = qm[0];
  #pragma unroll
  for (int g = 1; g < 8; ++g) M = fmaxf(M, qm[g]);
  if (t < 8) {
    const float be = __expf(qm[t] - M);
    bl[t]  = be;
    l8[t]  = be * qb[t*QSTR + 1];
    sx8[t] = be * qb[t*QSTR + 2];
    sy8[t] = be * qb[t*QSTR + 3];
  }
  __syncthreads();
  float L = 0.f;
  #pragma unroll
  for (int g = 0; g < 8; ++g) L += l8[g];
  const float invL = 1.0f / L;
  {
    float s = 0.f;
    #pragma unroll
    for (int g = 0; g < 8; ++g) s += bl[g] * qb[g*QSTR + 4 + t];
    SXs[t] = s * invL;
  }
  __syncthreads();

  #pragma unroll
  for (int r = 0; r < 4; ++r) {
    const int e = t + 64*r;
    float v = bv[e];
    const float* wvr = Wv + e*64;
    #pragma unroll 8
    for (int c = 0; c < 64; ++c) v += wvr[c] * SXs[c];
    out[(b*8 + h)*256 + e] = v;
  }
  if (t == 0) {
    float spx = 0.f, spy = 0.f;
    #pragma unroll
    for (int g = 0; g < 8; ++g) { spx += sx8[g]; spy += sy8[g]; }
    out[16384 + (b*8 + h)*2 + 0] = spx * invL;
    out[16384 + (b*8 + h)*2 + 1] = spy * invL;
  }
}

extern "C" void kernel_launch(void* const* d_in, const int* in_sizes, int n_in,
                              void* d_out, int out_size, void* d_ws, size_t ws_size,
                              hipStream_t stream)
{
  const float* x   = (const float*)d_in[0];
  const float* z   = (const float*)d_in[1];
  const float* pos = (const float*)d_in[2];
  const float* Wq  = (const float*)d_in[3];
  const float* bq  = (const float*)d_in[4];
  const float* Wk  = (const float*)d_in[5];
  const float* bk  = (const float*)d_in[6];
  const float* Wv  = (const float*)d_in[7];
  const float* bv  = (const float*)d_in[8];
  const float* Wp  = (const float*)d_in[9];
  const float* bp  = (const float*)d_in[10];
  float* out = (float*)d_out;
  float* ws  = (float*)d_ws;

  float* Weff = ws + OFF_W;
  float* Cj   = ws + OFF_CJ;
  float* Pm   = ws + OFF_PM;
  float* Pl   = ws + OFF_PL;
  float* Psp  = ws + OFF_PSP;
  float* Psx  = ws + OFF_PSX;
  float* Q    = ws + OFF_Q;

  // 67072 B dynamic LDS (> 64 KB default) — host-side, graph-safe, idempotent
  (void)hipFuncSetAttribute((const void*)main_kernel,
                            hipFuncAttributeMaxDynamicSharedMemorySize, SMEM1_BYTES);

  prep_kernel   <<<dim3(8,8),     64,  0,           stream>>>(z, Wq, bq, Wk, bk, Wp, bp, Weff, Cj);
  main_kernel   <<<dim3(NBLK,8),  256, SMEM1_BYTES, stream>>>(x, pos, Weff, Cj, Pm, Pl, Psp, Psx);
  reduce1_kernel<<<dim3(8,8,8),   256, 0,           stream>>>(Pm, Pl, Psp, Psx, Q);
  reduce2_kernel<<<dim3(8,8),     64,  0,           stream>>>(Q, Wv, bv, out);
}

// Round 5
// 248.009 us; speedup vs baseline: 2.0435x; 2.0435x over previous
//
#include <hip/hip_runtime.h>

// Problem constants
#define NN    65536       // H*W (H=W=256)
#define NSUB  256         // n per block
#define NBLK  (NN/NSUB)   // 256 blocks per batch

typedef short bf16x8 __attribute__((ext_vector_type(8)));
typedef float f32x4v __attribute__((ext_vector_type(4)));
typedef unsigned short ushort_t;
typedef unsigned int uint_t;

// ---- main_kernel LDS layout (bytes) ----
#define XSTR   72                 // xs row stride in bf16 units (144 B, 16B-aligned)
#define XHI_B  0                  // bf16 [256][72]  = 36864 B
#define XLO_B  36864              // bf16 [256][72]  = 36864 B (aliased by lgacc after phase A)
#define LGA_B  36864              // f32  [256][28]  = 28672 B
#define LGSTR  28                 // 112 B rows -> 16B aligned b128 reads
#define RED_B  73728              // f32 red[128]
#define SMEM_BYTES 74240          // 2 blocks/CU (148480 <= 163840)

// ---- workspace byte offsets ----
#define WTHI_B  0                 // bf16 [8][32][64] = 32768 B (coeff-major, rows 24..31 zero)
#define WTLO_B  32768
#define CJ_B    65536             // f32 [8][24]
#define PM_B    66304             // f32 [8*NBLK*8]
#define PL_B    131840
#define PSP_B   197376            // f32 [..][2]
#define PSX_B   328448            // f32 [..][64] = 4 MB
#define Q_B     4522752           // f32 [8][8][8][68]
#define QSTR    68

// ---------- helpers ----------
__device__ __forceinline__ uint_t bf16_rne_bits(float f) {
  uint_t u = __float_as_uint(f);
  return (u + 0x7FFFu + ((u >> 16) & 1u)) >> 16;
}
template <int CTRL>
__device__ __forceinline__ float dpp_add(float x) {
  int t = __builtin_amdgcn_update_dpp(0, __float_as_int(x), CTRL, 0xf, 0xf, false);
  return x + __int_as_float(t);
}
template <int CTRL>
__device__ __forceinline__ float dpp_maxs(float x) {
  int t = __builtin_amdgcn_update_dpp((int)0xFF800000u, __float_as_int(x), CTRL, 0xf, 0xf, false);
  return fmaxf(x, __int_as_float(t));
}
// full-wave reductions on VALU (DPP), result uniform via readlane 63
// 0x111..0x118: row_shr 1/2/4/8; 0x142: row_bcast15; 0x143: row_bcast31
__device__ __forceinline__ float wave_sum(float x) {
  x = dpp_add<0x111>(x); x = dpp_add<0x112>(x); x = dpp_add<0x114>(x);
  x = dpp_add<0x118>(x); x = dpp_add<0x142>(x); x = dpp_add<0x143>(x);
  return __int_as_float(__builtin_amdgcn_readlane(__float_as_int(x), 63));
}
__device__ __forceinline__ float wave_max(float x) {
  x = dpp_maxs<0x111>(x); x = dpp_maxs<0x112>(x); x = dpp_maxs<0x114>(x);
  x = dpp_maxs<0x118>(x); x = dpp_maxs<0x142>(x); x = dpp_maxs<0x143>(x);
  return __int_as_float(__builtin_amdgcn_readlane(__float_as_int(x), 63));
}

// ---------------- K0: effective weights, split-bf16, B-fragment layout ----------------
// Weff[coeff=h*3+j][c] = sum_hd q[hd]*M_j[hd]*Wk[h*32+hd, c]; M_0=bp, M_1=Wp[:,0], M_2=Wp[:,1]
__global__ __launch_bounds__(64) void prep_kernel(
    const float* __restrict__ z,  const float* __restrict__ Wq, const float* __restrict__ bq,
    const float* __restrict__ Wk, const float* __restrict__ bk,
    const float* __restrict__ Wp, const float* __restrict__ bp,
    ushort_t* __restrict__ WThi, ushort_t* __restrict__ WTlo, float* __restrict__ Cj)
{
  const int h = blockIdx.x, b = blockIdx.y, t = threadIdx.x;
  __shared__ float q[32];
  if (t < 32) {
    const int e = h*32 + t;
    float a = bq[e];
    const float* zr = z + b*64;
    const float* wr = Wq + e*64;
    #pragma unroll 8
    for (int c = 0; c < 64; ++c) a += zr[c]*wr[c];
    q[t] = a;
  }
  __syncthreads();
  const int c = t;
  float w[3] = {0.f, 0.f, 0.f};
  #pragma unroll 4
  for (int hd = 0; hd < 32; ++hd) {
    const float qk = q[hd] * Wk[(h*32+hd)*64 + c];
    w[0] += qk * bp[hd];
    w[1] += qk * Wp[hd*2+0];
    w[2] += qk * Wp[hd*2+1];
  }
  #pragma unroll
  for (int j = 0; j < 3; ++j) {
    const int coeff = h*3 + j;
    const uint_t hb = bf16_rne_bits(w[j]);
    const float  fh = __uint_as_float(hb << 16);
    const uint_t lb = bf16_rne_bits(w[j] - fh);
    WThi[(b*32 + coeff)*64 + c] = (ushort_t)hb;
    WTlo[(b*32 + coeff)*64 + c] = (ushort_t)lb;
  }
  if (h == 0) {               // zero pad rows 24..31
    #pragma unroll
    for (int r = 0; r < 8; ++r) {
      WThi[(b*32 + 24 + r)*64 + c] = 0;
      WTlo[(b*32 + 24 + r)*64 + c] = 0;
    }
  }
  if (t < 3) {
    float s = 0.f;
    for (int hd = 0; hd < 32; ++hd) {
      const float m = (t == 0) ? bp[hd] : Wp[hd*2 + (t-1)];
      s += q[hd] * m * bk[h*32+hd];
    }
    Cj[b*24 + h*3 + t] = s;
  }
}

// ---------------- K1: MFMA logits + softmax partials + weighted-x ----------------
__global__ __launch_bounds__(256, 2) void main_kernel(
    const float* __restrict__ x, const float* __restrict__ pos,
    const ushort_t* __restrict__ WThi, const ushort_t* __restrict__ WTlo,
    const float* __restrict__ Cj,
    float* __restrict__ Pm, float* __restrict__ Pl,
    float* __restrict__ Psp, float* __restrict__ Psx)
{
  extern __shared__ char smc[];
  ushort_t* xhi = (ushort_t*)(smc + XHI_B);
  ushort_t* xlo = (ushort_t*)(smc + XLO_B);
  float*    lga = (float*)(smc + LGA_B);
  float*    red = (float*)(smc + RED_B);
  const int t   = threadIdx.x;
  const int blk = blockIdx.x;
  const int b   = blockIdx.y;
  const int n0  = blk * NSUB;
  const int wid = t >> 6, lid = t & 63;
  const int c0  = lid & 15, q4 = lid >> 4;

  // ---- B-fragments (global, L2-hot; block-uniform rows, per-lane 16B) ----
  bf16x8 bh[2][2], bl[2][2];
  {
    const ushort_t* wtb_h = WThi + b*2048;
    const ushort_t* wtb_l = WTlo + b*2048;
    #pragma unroll
    for (int nt = 0; nt < 2; ++nt)
      #pragma unroll
      for (int ks = 0; ks < 2; ++ks) {
        const int off = (nt*16 + c0)*64 + ks*32 + q4*8;
        bh[nt][ks] = *(const bf16x8*)(wtb_h + off);
        bl[nt][ks] = *(const bf16x8*)(wtb_l + off);
      }
  }

  // ---- stage x[b,:,n0+t] -> bf16 hi/lo in LDS (chunked: no spills) ----
  {
    const float* xg = x + (size_t)b*64*NN + n0 + t;
    #pragma unroll
    for (int cc = 0; cc < 4; ++cc) {
      float v[16];
      #pragma unroll
      for (int i = 0; i < 16; ++i) v[i] = xg[(size_t)(cc*16+i)*NN];
      uint_t hb[16], lb[16];
      #pragma unroll
      for (int i = 0; i < 16; ++i) {
        hb[i] = bf16_rne_bits(v[i]);
        lb[i] = bf16_rne_bits(v[i] - __uint_as_float(hb[i] << 16));
      }
      uint4 H0 = make_uint4(hb[0]|(hb[1]<<16), hb[2]|(hb[3]<<16), hb[4]|(hb[5]<<16), hb[6]|(hb[7]<<16));
      uint4 H1 = make_uint4(hb[8]|(hb[9]<<16), hb[10]|(hb[11]<<16), hb[12]|(hb[13]<<16), hb[14]|(hb[15]<<16));
      uint4 L0 = make_uint4(lb[0]|(lb[1]<<16), lb[2]|(lb[3]<<16), lb[4]|(lb[5]<<16), lb[6]|(lb[7]<<16));
      uint4 L1 = make_uint4(lb[8]|(lb[9]<<16), lb[10]|(lb[11]<<16), lb[12]|(lb[13]<<16), lb[14]|(lb[15]<<16));
      char* dh = smc + XHI_B + t*144 + cc*32;
      char* dl = smc + XLO_B + t*144 + cc*32;
      *(uint4*)(dh)      = H0;  *(uint4*)(dh + 16) = H1;
      *(uint4*)(dl)      = L0;  *(uint4*)(dl + 16) = L1;
    }
  }

  // block-uniform params -> SGPRs
  float cj[24];
  {
    const float* cjp = Cj + b*24;
    #pragma unroll
    for (int k = 0; k < 24; ++k) cj[k] = cjp[k];
  }
  float rxh[8], py[8];
  #pragma unroll
  for (int h = 0; h < 8; ++h) {
    rxh[h] = (float)blk - pos[(b*8+h)*2 + 0];   // gx == n>>8 == blk (block-uniform)
    py[h]  = pos[(b*8+h)*2 + 1];
  }

  __syncthreads();   // (1) xs ready

  // ---- phase A: D[pixel, coeff] = X(hi+lo) . W^T(hi+lo), 3-term split ----
  f32x4v acc[4][2];
  #pragma unroll
  for (int mt = 0; mt < 4; ++mt) { acc[mt][0] = (f32x4v)0.f; acc[mt][1] = (f32x4v)0.f; }
  {
    const int mrow0 = wid*64;
    #pragma unroll
    for (int mt = 0; mt < 4; ++mt) {
      const int row = mrow0 + mt*16 + c0;         // A: m = lane&15
      const ushort_t* ph = xhi + row*XSTR + q4*8; // k = quad*8+j
      const ushort_t* pl = xlo + row*XSTR + q4*8;
      bf16x8 ah0 = *(const bf16x8*)(ph);
      bf16x8 ah1 = *(const bf16x8*)(ph + 32);
      bf16x8 al0 = *(const bf16x8*)(pl);
      bf16x8 al1 = *(const bf16x8*)(pl + 32);
      #pragma unroll
      for (int nt = 0; nt < 2; ++nt) {
        f32x4v a = acc[mt][nt];
        a = __builtin_amdgcn_mfma_f32_16x16x32_bf16(ah0, bh[nt][0], a, 0, 0, 0);
        a = __builtin_amdgcn_mfma_f32_16x16x32_bf16(ah1, bh[nt][1], a, 0, 0, 0);
        a = __builtin_amdgcn_mfma_f32_16x16x32_bf16(ah0, bl[nt][0], a, 0, 0, 0);
        a = __builtin_amdgcn_mfma_f32_16x16x32_bf16(ah1, bl[nt][1], a, 0, 0, 0);
        a = __builtin_amdgcn_mfma_f32_16x16x32_bf16(al0, bh[nt][0], a, 0, 0, 0);
        a = __builtin_amdgcn_mfma_f32_16x16x32_bf16(al1, bh[nt][1], a, 0, 0, 0);
        acc[mt][nt] = a;
      }
    }
  }
  __syncthreads();   // (2) all xs_lo reads done -> safe to alias lga

  // C-layout: col(coeff) = lane&15 (+16*nt), row(pixel) = quad*4 + reg
  {
    const int mrow0 = wid*64;
    #pragma unroll
    for (int mt = 0; mt < 4; ++mt)
      #pragma unroll
      for (int r = 0; r < 4; ++r) {
        const int prow = mrow0 + mt*16 + q4*4 + r;
        lga[prow*LGSTR + c0] = acc[mt][0][r];
        if (c0 < 8) lga[prow*LGSTR + 16 + c0] = acc[mt][1][r];
      }
  }
  __syncthreads();   // (3) lga ready

  // ---- per-thread logit assembly (pixel = t) ----
  float a24[24];
  {
    const float4* ap = (const float4*)(lga + t*LGSTR);
    #pragma unroll
    for (int r = 0; r < 6; ++r) *(float4*)(a24 + 4*r) = ap[r];
  }
  const float tf = (float)t;            // gy == n&255 == t
  float lg[8];
  #pragma unroll
  for (int h = 0; h < 8; ++h) {
    const float a0 = a24[h*3+0] + cj[h*3+0];
    const float a1 = a24[h*3+1] + cj[h*3+1];
    const float a2 = a24[h*3+2] + cj[h*3+2];
    lg[h] = (a0 + rxh[h]*a1 + (tf - py[h])*a2) * 0.17677669529663687f;
  }

  // ---- block max per head (DPP on VALU pipe) ----
  #pragma unroll
  for (int h = 0; h < 8; ++h) {
    const float m = wave_max(lg[h]);
    if (lid == 0) red[h*4 + wid] = m;
  }
  __syncthreads();   // (4)

  float p[8];
  #pragma unroll
  for (int h = 0; h < 8; ++h) {
    const float M = fmaxf(fmaxf(red[h*4+0], red[h*4+1]), fmaxf(red[h*4+2], red[h*4+3]));
    p[h] = __expf(lg[h] - M);
  }
  #pragma unroll
  for (int h = 0; h < 8; ++h) {
    const float sp  = wave_sum(p[h]);
    const float spj = wave_sum(p[h] * tf);
    if (lid == 0) { red[32 + h*4 + wid] = sp; red[64 + h*4 + wid] = spj; }
  }
  __syncthreads();   // (5)

  if (t < 8) {
    const int base = (b*NBLK + blk)*8 + t;
    const float M = fmaxf(fmaxf(red[t*4+0], red[t*4+1]), fmaxf(red[t*4+2], red[t*4+3]));
    const float L  = red[32+t*4+0] + red[32+t*4+1] + red[32+t*4+2] + red[32+t*4+3];
    const float SJ = red[64+t*4+0] + red[64+t*4+1] + red[64+t*4+2] + red[64+t*4+3];
    Pm[base] = M;
    Pl[base] = L;
    Psp[base*2+0] = (float)blk * L;
    Psp[base*2+1] = SJ;
  }

  // ---- phase B: aB[h][c=lid] = sum_{j in quarter} p[h][j] * x[j][c] ----
  // p via v_readlane (VALU), x via bf16 b16 LDS reads (2-way, free)
  float aB[8];
  #pragma unroll
  for (int h = 0; h < 8; ++h) aB[h] = 0.f;
  {
    const ushort_t* xrow = xhi + (wid*64)*XSTR + lid;
    #pragma unroll 8
    for (int j = 0; j < 64; ++j) {
      const float xv = __uint_as_float(((uint_t)xrow[j*XSTR]) << 16);
      #pragma unroll
      for (int h = 0; h < 8; ++h) {
        const float pj = __int_as_float(__builtin_amdgcn_readlane(__float_as_int(p[h]), j));
        aB[h] = fmaf(pj, xv, aB[h]);
      }
    }
  }
  __syncthreads();   // (6) xs_hi reads done -> reuse region for partials
  {
    float* pstage = (float*)smc;         // [4][8][64]
    #pragma unroll
    for (int h = 0; h < 8; ++h) pstage[(wid*8 + h)*64 + lid] = aB[h];
  }
  __syncthreads();   // (7)
  {
    const float* pstage = (const float*)smc;
    const size_t pb = ((size_t)(b*NBLK + blk))*8;
    #pragma unroll
    for (int r = 0; r < 2; ++r) {
      const int idx = t + 256*r;          // (h,c) flat
      const float s = pstage[idx] + pstage[512+idx] + pstage[1024+idx] + pstage[1536+idx];
      Psx[pb*64 + idx] = s;
    }
  }
}

// ---------------- K2a: combine 32 blocks per (b,h,g) ----------------
__global__ __launch_bounds__(256) void reduce1_kernel(
    const float* __restrict__ Pm, const float* __restrict__ Pl,
    const float* __restrict__ Psp, const float* __restrict__ Psx,
    float* __restrict__ Q)
{
  const int g = blockIdx.x, h = blockIdx.y, b = blockIdx.z, t = threadIdx.x;
  __shared__ float al[32];
  __shared__ float mgs;
  __shared__ float sums[3];
  __shared__ float sxl[256];
  const int base = (b*NBLK + g*32)*8 + h;

  float m_t = -1e30f;
  if (t < 32) m_t = Pm[base + t*8];
  if (t < 64) {
    float mm = m_t;
    #pragma unroll
    for (int off = 16; off >= 1; off >>= 1) mm = fmaxf(mm, __shfl_xor(mm, off, 64));
    if (t == 0) mgs = mm;
  }
  __syncthreads();
  const float Mg = mgs;
  if (t < 32) {
    const float a = __expf(m_t - Mg);
    al[t] = a;
    float lt = Pl[base + t*8] * a;
    float sx = Psp[(base + t*8)*2 + 0] * a;
    float sy = Psp[(base + t*8)*2 + 1] * a;
    #pragma unroll
    for (int off = 16; off >= 1; off >>= 1) {
      lt += __shfl_xor(lt, off, 64);
      sx += __shfl_xor(sx, off, 64);
      sy += __shfl_xor(sy, off, 64);
    }
    if (t == 0) { sums[0] = lt; sums[1] = sx; sums[2] = sy; }
  }
  __syncthreads();
  {
    const int c = t & 63, g2 = t >> 6;
    float acc = 0.f;
    #pragma unroll
    for (int i = 0; i < 8; ++i) {
      const int k = g2*8 + i;
      acc += al[k] * Psx[(size_t)(base + k*8)*64 + c];
    }
    sxl[g2*64 + c] = acc;
  }
  __syncthreads();
  float* q = Q + ((b*8 + h)*8 + g)*QSTR;
  if (t < 64) q[4+t] = sxl[t] + sxl[64+t] + sxl[128+t] + sxl[192+t];
  if (t == 0) { q[0] = Mg; q[1] = sums[0]; q[2] = sums[1]; q[3] = sums[2]; }
}

// ---------------- K2b: final combine + value projection ----------------
__global__ __launch_bounds__(64) void reduce2_kernel(
    const float* __restrict__ Q, const float* __restrict__ Wv, const float* __restrict__ bv,
    float* __restrict__ out)
{
  const int h = blockIdx.x, b = blockIdx.y, t = threadIdx.x;
  __shared__ float qm[8], bl[8], l8[8], sx8[8], sy8[8];
  __shared__ float SXs[64];
  const float* qb = Q + ((b*8 + h)*8)*QSTR;

  if (t < 8) qm[t] = qb[t*QSTR + 0];
  __syncthreads();
  float M = qm[0];
  #pragma unroll
  for (int g = 1; g < 8; ++g) M = fmaxf(M, qm[g]);
  if (t < 8) {
    const float be = __expf(qm[t] - M);
    bl[t]  = be;
    l8[t]  = be * qb[t*QSTR + 1];
    sx8[t] = be * qb[t*QSTR + 2];
    sy8[t] = be * qb[t*QSTR + 3];
  }
  __syncthreads();
  float L = 0.f;
  #pragma unroll
  for (int g = 0; g < 8; ++g) L += l8[g];
  const float invL = 1.0f / L;
  {
    float s = 0.f;
    #pragma unroll
    for (int g = 0; g < 8; ++g) s += bl[g] * qb[g*QSTR + 4 + t];
    SXs[t] = s * invL;
  }
  __syncthreads();

  #pragma unroll
  for (int r = 0; r < 4; ++r) {
    const int e = t + 64*r;
    float v = bv[e];
    const float* wvr = Wv + e*64;
    #pragma unroll 8
    for (int c = 0; c < 64; ++c) v += wvr[c] * SXs[c];
    out[(b*8 + h)*256 + e] = v;
  }
  if (t == 0) {
    float spx = 0.f, spy = 0.f;
    #pragma unroll
    for (int g = 0; g < 8; ++g) { spx += sx8[g]; spy += sy8[g]; }
    out[16384 + (b*8 + h)*2 + 0] = spx * invL;
    out[16384 + (b*8 + h)*2 + 1] = spy * invL;
  }
}

extern "C" void kernel_launch(void* const* d_in, const int* in_sizes, int n_in,
                              void* d_out, int out_size, void* d_ws, size_t ws_size,
                              hipStream_t stream)
{
  const float* x   = (const float*)d_in[0];
  const float* z   = (const float*)d_in[1];
  const float* pos = (const float*)d_in[2];
  const float* Wq  = (const float*)d_in[3];
  const float* bq  = (const float*)d_in[4];
  const float* Wk  = (const float*)d_in[5];
  const float* bk  = (const float*)d_in[6];
  const float* Wv  = (const float*)d_in[7];
  const float* bv  = (const float*)d_in[8];
  const float* Wp  = (const float*)d_in[9];
  const float* bp  = (const float*)d_in[10];
  float* out = (float*)d_out;
  char*  wsb = (char*)d_ws;

  ushort_t* WThi = (ushort_t*)(wsb + WTHI_B);
  ushort_t* WTlo = (ushort_t*)(wsb + WTLO_B);
  float* Cj  = (float*)(wsb + CJ_B);
  float* Pm  = (float*)(wsb + PM_B);
  float* Pl  = (float*)(wsb + PL_B);
  float* Psp = (float*)(wsb + PSP_B);
  float* Psx = (float*)(wsb + PSX_B);
  float* Q   = (float*)(wsb + Q_B);

  // 74240 B dynamic LDS (> 64 KB default) — host-side, graph-safe, idempotent
  (void)hipFuncSetAttribute((const void*)main_kernel,
                            hipFuncAttributeMaxDynamicSharedMemorySize, SMEM_BYTES);

  prep_kernel   <<<dim3(8,8),    64,  0,          stream>>>(z, Wq, bq, Wk, bk, Wp, bp, WThi, WTlo, Cj);
  main_kernel   <<<dim3(NBLK,8), 256, SMEM_BYTES, stream>>>(x, pos, WThi, WTlo, Cj, Pm, Pl, Psp, Psx);
  reduce1_kernel<<<dim3(8,8,8),  256, 0,          stream>>>(Pm, Pl, Psp, Psx, Q);
  reduce2_kernel<<<dim3(8,8),    64,  0,          stream>>>(Q, Wv, bv, out);
}